// Round 12
// baseline (602.775 us; speedup 1.0000x reference)
//
#include <hip/hip_runtime.h>
#include <cfloat>

#define B_TOTAL 131072
#define N_CB    1024
#define DIM     64
#define DEPTH   4
#define BM      128     // rows per block (4 waves x 32)
#define RS      68      // res row stride (floats)
#define EPS     0.075f  // band: covers bf16-split coarse err + 13-bit key truncation

typedef __bf16 bf16x8 __attribute__((ext_vector_type(8)));
typedef unsigned short u16x8 __attribute__((ext_vector_type(8)));
typedef float f32x16 __attribute__((ext_vector_type(16)));

#define MFMA(a, b, c) __builtin_amdgcn_mfma_f32_32x32x16_bf16(a, b, c, 0, 0, 0)

static __device__ __forceinline__ unsigned umin32(unsigned a, unsigned b) { return a < b ? a : b; }
static __device__ __forceinline__ unsigned umax32(unsigned a, unsigned b) { return a > b ? a : b; }

static __device__ __forceinline__ unsigned short f2bf(float f) {
  unsigned u = __builtin_bit_cast(unsigned, f);
  return (unsigned short)((u + 0x7fffu + ((u >> 16) & 1u)) >> 16);
}
static __device__ __forceinline__ float bf2f(unsigned short h) {
  unsigned u = ((unsigned)h) << 16;
  return __builtin_bit_cast(float, u);
}

// Pre-split codebook into MFMA B-fragment layout (bh/bl) + fp32 norms.
// frag element: [(t*4+m)*64 + lane][j] = cb[32t + (lane&31)][16m + 8*(lane>>5) + j]
__global__ void prep_kernel(const float* __restrict__ cb,
                            unsigned short* __restrict__ bh,
                            unsigned short* __restrict__ bl,
                            float* __restrict__ c2) {
  const int t = blockIdx.x;            // 0..31
  const int l = threadIdx.x;           // 0..63
  const int tc = l & 31, hi = l >> 5;
  const int row = 32 * t + tc;
  #pragma unroll
  for (int m = 0; m < 4; ++m) {
    const float* p = cb + row * DIM + 16 * m + 8 * hi;
    const size_t o = (((size_t)t * 4 + m) * 64 + l) * 8;
    #pragma unroll
    for (int j = 0; j < 8; ++j) {
      float f = p[j];
      unsigned short h = f2bf(f);
      bh[o + j] = h;
      bl[o + j] = f2bf(f - bf2f(h));
    }
  }
  if (hi == 0) {
    const float* p = cb + row * DIM;
    float s = 0.f;
    #pragma unroll
    for (int k = 0; k < DIM; ++k) s += p[k] * p[k];
    c2[row] = s;
  }
}

// LDS: res 34816 + c2s 4096 + z2s 512 + preds 512 = 39936 B
// (256,2): 256-reg cap -> 2-deep double-buffered B-frags fit with zero spill.
__global__ __launch_bounds__(256, 2)
void rvq_mfma_kernel(const float* __restrict__ z,
                     const float* __restrict__ cbg,
                     const unsigned short* __restrict__ bh,
                     const unsigned short* __restrict__ bl,
                     const float* __restrict__ c2g,
                     float* __restrict__ out) {
  __shared__ __align__(16) float res[BM][RS];  // fp32 residual, per-wave 32-row panels
  __shared__ float c2s[N_CB];
  __shared__ float z2s[BM];
  __shared__ int   preds[BM];

  const int tid  = threadIdx.x;
  const int wave = tid >> 6;
  const int l    = tid & 63;
  const int tc   = l & 31;
  const int hi   = l >> 5;
  const int wr   = wave * 32;
  const int row0 = blockIdx.x * BM;

  float* zq   = out;
  float* maps = out + (size_t)B_TOTAL * DIM;

  // ---- stage z -> res (coalesced), c2 -> LDS ----
  {
    const float4* z4 = (const float4*)(z + (size_t)row0 * DIM);
    #pragma unroll
    for (int i = 0; i < 8; ++i) {
      const int f = i * 256 + tid;
      float4 v = z4[f];
      const int r = (f * 4) >> 6, d0 = (f * 4) & 63;
      *(float4*)&res[r][d0] = v;
    }
    for (int i = tid; i < N_CB; i += 256) c2s[i] = c2g[i];
  }
  __syncthreads();

  const bf16x8* bbase = (const bf16x8*)bh;
  const bf16x8* lbase = (const bf16x8*)bl;

  for (int depth = 0; depth < DEPTH; ++depth) {
    // ---- A fragments (split bf16) + fp32 row norm ----
    bf16x8 Ah[4], Al[4];
    float zp = 0.f;
    {
      const int arow = wr + tc;
      #pragma unroll
      for (int m = 0; m < 4; ++m) {
        u16x8 uh, ul;
        #pragma unroll
        for (int jj = 0; jj < 8; ++jj) {
          const float f = res[arow][16 * m + 8 * hi + jj];
          zp += f * f;
          const unsigned short h = f2bf(f);
          uh[jj] = h;
          ul[jj] = f2bf(f - bf2f(h));
        }
        Ah[m] = __builtin_bit_cast(bf16x8, uh);
        Al[m] = __builtin_bit_cast(bf16x8, ul);
      }
    }
    zp += __shfl_xor(zp, 32);          // partner lane holds the other 32 dims
    if (l < 32) z2s[wr + l] = zp;

    // acc seed: C-in = -z2(row)/2, so acc_final = dot - z2/2, d = c2 - 2*acc
    f32x16 accInit;
    #pragma unroll
    for (int s = 0; s < 16; ++s)
      accInit[s] = -0.5f * z2s[wr + (s & 3) + 8 * (s >> 2) + 4 * hi];

    // packed top-2 keys: (dist_bits & ~1023) | col ; uint order == (dist, col) order
    unsigned m1[16], m2[16];
    #pragma unroll
    for (int s = 0; s < 16; ++s) { m1[s] = 0xFFFFFFFFu; m2[s] = 0xFFFFFFFFu; }

    float* mbase = maps + ((size_t)depth * B_TOTAL + row0 + wr + 4 * hi) * N_CB + tc;

    // ---- prologue: 2-deep prefetch (tiles 0 and 1) ----
    bf16x8 B0, B1, B2, B3, L0, L1, L2, L3;   // even-tile buffer
    bf16x8 C0, C1, C2, C3, D0, D1, D2, D3;   // odd-tile buffer
    {
      const bf16x8* p0 = bbase + l;
      const bf16x8* q0 = lbase + l;
      B0 = p0[0]; B1 = p0[64]; B2 = p0[128]; B3 = p0[192];
      L0 = q0[0]; L1 = q0[64]; L2 = q0[128]; L3 = q0[192];
      const bf16x8* p1 = bbase + (size_t)(1 * 4) * 64 + l;
      const bf16x8* q1 = lbase + (size_t)(1 * 4) * 64 + l;
      C0 = p1[0]; C1 = p1[64]; C2 = p1[128]; C3 = p1[192];
      D0 = q1[0]; D1 = q1[64]; D2 = q1[128]; D3 = q1[192];
    }

    for (int t = 0; t < 32; t += 2) {
      // ===== even tile t: compute with B/L, then refill B/L with tile t+2 =====
      {
        f32x16 acc = MFMA(Ah[0], B0, accInit);
        acc = MFMA(Ah[1], B1, acc);
        acc = MFMA(Ah[2], B2, acc);
        acc = MFMA(Ah[3], B3, acc);
        acc = MFMA(Ah[0], L0, acc);
        acc = MFMA(Ah[1], L1, acc);
        acc = MFMA(Ah[2], L2, acc);
        acc = MFMA(Ah[3], L3, acc);
        acc = MFMA(Al[0], B0, acc);
        acc = MFMA(Al[1], B1, acc);
        acc = MFMA(Al[2], B2, acc);
        acc = MFMA(Al[3], B3, acc);

        const int tn = (t + 2) & 31;
        const bf16x8* pn = bbase + (size_t)(tn * 4) * 64 + l;
        const bf16x8* qn = lbase + (size_t)(tn * 4) * 64 + l;
        B0 = pn[0]; B1 = pn[64]; B2 = pn[128]; B3 = pn[192];
        L0 = qn[0]; L1 = qn[64]; L2 = qn[128]; L3 = qn[192];

        const float c2v = c2s[32 * t + tc];
        const unsigned colp = (unsigned)(32 * t + tc);
        float* mp = mbase + 32 * t;
        #pragma unroll
        for (int s = 0; s < 16; ++s) {
          const float d = fmaf(-2.f, acc[s], c2v);
          mp[((s & 3) + 8 * (s >> 2)) * N_CB] = d;   // 2x128B segments per wave store
          const float dc = fmaxf(d, 0.f);
          const unsigned k = (__builtin_bit_cast(unsigned, dc) & 0xFFFFFC00u) | colp;
          const unsigned t2 = umax32(m1[s], k);
          m1[s] = umin32(m1[s], k);
          m2[s] = umin32(m2[s], t2);
        }
      }
      // ===== odd tile t+1: compute with C/D, then refill C/D with tile t+3 =====
      {
        f32x16 acc = MFMA(Ah[0], C0, accInit);
        acc = MFMA(Ah[1], C1, acc);
        acc = MFMA(Ah[2], C2, acc);
        acc = MFMA(Ah[3], C3, acc);
        acc = MFMA(Ah[0], D0, acc);
        acc = MFMA(Ah[1], D1, acc);
        acc = MFMA(Ah[2], D2, acc);
        acc = MFMA(Ah[3], D3, acc);
        acc = MFMA(Al[0], C0, acc);
        acc = MFMA(Al[1], C1, acc);
        acc = MFMA(Al[2], C2, acc);
        acc = MFMA(Al[3], C3, acc);

        const int tn = (t + 3) & 31;
        const bf16x8* pn = bbase + (size_t)(tn * 4) * 64 + l;
        const bf16x8* qn = lbase + (size_t)(tn * 4) * 64 + l;
        C0 = pn[0]; C1 = pn[64]; C2 = pn[128]; C3 = pn[192];
        D0 = qn[0]; D1 = qn[64]; D2 = qn[128]; D3 = qn[192];

        const int tt = t + 1;
        const float c2v = c2s[32 * tt + tc];
        const unsigned colp = (unsigned)(32 * tt + tc);
        float* mp = mbase + 32 * tt;
        #pragma unroll
        for (int s = 0; s < 16; ++s) {
          const float d = fmaf(-2.f, acc[s], c2v);
          mp[((s & 3) + 8 * (s >> 2)) * N_CB] = d;
          const float dc = fmaxf(d, 0.f);
          const unsigned k = (__builtin_bit_cast(unsigned, dc) & 0xFFFFFC00u) | colp;
          const unsigned t2 = umax32(m1[s], k);
          m1[s] = umin32(m1[s], k);
          m2[s] = umin32(m2[s], t2);
        }
      }
    }

    // ---- decide pred per row; fp64 exact refine when band is ambiguous ----
    #pragma unroll
    for (int s = 0; s < 16; ++s) {
      const int row = wr + (s & 3) + 8 * (s >> 2) + 4 * hi;
      unsigned g1 = m1[s], g2 = m2[s];
      #pragma unroll
      for (int msk = 1; msk < 32; msk <<= 1) {
        const unsigned o1 = (unsigned)__shfl_xor((int)g1, msk);
        const unsigned o2 = (unsigned)__shfl_xor((int)g2, msk);
        const unsigned hi2 = umax32(g1, o1);
        g1 = umin32(g1, o1);
        g2 = umin32(umin32(g2, o2), hi2);
      }
      int pred = (int)(g1 & 1023u);
      const float d1f = __builtin_bit_cast(float, g1 & 0xFFFFFC00u);
      const float d2f = __builtin_bit_cast(float, g2 & 0xFFFFFC00u);
      if (d2f <= d1f + EPS) {
        const float thr = d1f + EPS;
        const bool c1 = __builtin_bit_cast(float, m1[s] & 0xFFFFFC00u) <= thr;
        const bool c2b = __builtin_bit_cast(float, m2[s] & 0xFFFFFC00u) <= thr;
        const unsigned long long B1b = __ballot(c1);
        const unsigned long long B2b = __ballot(c2b);
        const unsigned sh = tid & 32;
        unsigned b1 = (unsigned)(B1b >> sh);
        unsigned b2 = (unsigned)(B2b >> sh);
        const float2 rv = *(const float2*)&res[row][2 * tc];
        double best = DBL_MAX; int bix = 0x7fffffff;
        unsigned rem = b1;
        while (rem) {
          const int lb = __ffs(rem) - 1; rem &= rem - 1;
          const int cidx = __shfl((int)(m1[s] & 1023u), lb, 32);
          const float2 cv = *(const float2*)(cbg + (size_t)cidx * DIM + 2 * tc);
          double dp = ((double)rv.x - cv.x) * ((double)rv.x - cv.x)
                    + ((double)rv.y - cv.y) * ((double)rv.y - cv.y);
          #pragma unroll
          for (int msk = 1; msk < 32; msk <<= 1) dp += __shfl_xor(dp, msk);
          if (dp < best || (dp == best && cidx < bix)) { best = dp; bix = cidx; }
        }
        rem = b2;
        while (rem) {
          const int lb = __ffs(rem) - 1; rem &= rem - 1;
          const int cidx = __shfl((int)(m2[s] & 1023u), lb, 32);
          const float2 cv = *(const float2*)(cbg + (size_t)cidx * DIM + 2 * tc);
          double dp = ((double)rv.x - cv.x) * ((double)rv.x - cv.x)
                    + ((double)rv.y - cv.y) * ((double)rv.y - cv.y);
          #pragma unroll
          for (int msk = 1; msk < 32; msk <<= 1) dp += __shfl_xor(dp, msk);
          if (dp < best || (dp == best && cidx < bix)) { best = dp; bix = cidx; }
        }
        pred = bix;
      }
      if (tc == 0) preds[row] = pred;
    }

    // ---- residual -= codebook[pred] (fp32 elementwise, bitwise = ref) ----
    {
      const int urow = wr + tc;
      const int p = preds[urow];
      const float4* crow = (const float4*)(cbg + (size_t)p * DIM + 32 * hi);
      #pragma unroll
      for (int q = 0; q < 8; ++q) {
        const float4 cv = crow[q];
        float4* rp = (float4*)&res[urow][32 * hi + 4 * q];
        float4 rv = *rp;
        rv.x -= cv.x; rv.y -= cv.y; rv.z -= cv.z; rv.w -= cv.w;
        *rp = rv;
      }
    }
    // depth-loop state is wave-private; no block barrier needed
  }

  __syncthreads();   // final epilogue reads the whole panel across waves

  // ---- z_q = z - residual_final ----
  {
    const float4* z4 = (const float4*)(z + (size_t)row0 * DIM);
    float4* o4 = (float4*)(zq + (size_t)row0 * DIM);
    #pragma unroll
    for (int i = 0; i < 8; ++i) {
      const int f = i * 256 + tid;
      float4 v = z4[f];
      const int r = (f * 4) >> 6, d0 = (f * 4) & 63;
      const float4 rv = *(const float4*)&res[r][d0];
      v.x -= rv.x; v.y -= rv.y; v.z -= rv.z; v.w -= rv.w;
      o4[f] = v;
    }
  }
}

extern "C" void kernel_launch(void* const* d_in, const int* in_sizes, int n_in,
                              void* d_out, int out_size, void* d_ws, size_t ws_size,
                              hipStream_t stream) {
  const float* z  = (const float*)d_in[0];
  const float* cb = (const float*)d_in[1];
  float* out = (float*)d_out;

  unsigned short* bh = (unsigned short*)d_ws;          // 65536 u16 = 128KB
  unsigned short* bl = bh + 65536;                     // 128KB
  float*          c2 = (float*)(bl + 65536);           // 4KB

  hipLaunchKernelGGL(prep_kernel, dim3(32), dim3(64), 0, stream, cb, bh, bl, c2);
  hipLaunchKernelGGL(rvq_mfma_kernel, dim3(B_TOTAL / BM), dim3(256), 0, stream,
                     z, cb, bh, bl, c2, out);
}

// Round 13
// 524.591 us; speedup vs baseline: 1.1490x; 1.1490x over previous
//
#include <hip/hip_runtime.h>
#include <cfloat>

#define B_TOTAL 131072
#define N_CB    1024
#define DIM     64
#define DEPTH   4
#define BM      128     // rows per block (4 waves x 32)
#define RS      68      // res row stride (floats)
#define EPS     0.075f  // band: covers bf16-split coarse err + 13-bit key truncation

typedef __bf16 bf16x8 __attribute__((ext_vector_type(8)));
typedef unsigned short u16x8 __attribute__((ext_vector_type(8)));
typedef float f32x16 __attribute__((ext_vector_type(16)));

#define MFMA(a, b, c) __builtin_amdgcn_mfma_f32_32x32x16_bf16(a, b, c, 0, 0, 0)

static __device__ __forceinline__ unsigned umin32(unsigned a, unsigned b) { return a < b ? a : b; }
static __device__ __forceinline__ unsigned umax32(unsigned a, unsigned b) { return a > b ? a : b; }

static __device__ __forceinline__ unsigned short f2bf(float f) {
  unsigned u = __builtin_bit_cast(unsigned, f);
  return (unsigned short)((u + 0x7fffu + ((u >> 16) & 1u)) >> 16);
}
static __device__ __forceinline__ float bf2f(unsigned short h) {
  unsigned u = ((unsigned)h) << 16;
  return __builtin_bit_cast(float, u);
}

// Pre-split codebook into MFMA B-fragment layout (bh/bl) + fp32 norms.
// frag element: [(t*4+m)*64 + lane][j] = cb[32t + (lane&31)][16m + 8*(lane>>5) + j]
__global__ void prep_kernel(const float* __restrict__ cb,
                            unsigned short* __restrict__ bh,
                            unsigned short* __restrict__ bl,
                            float* __restrict__ c2) {
  const int t = blockIdx.x;            // 0..31
  const int l = threadIdx.x;           // 0..63
  const int tc = l & 31, hi = l >> 5;
  const int row = 32 * t + tc;
  #pragma unroll
  for (int m = 0; m < 4; ++m) {
    const float* p = cb + row * DIM + 16 * m + 8 * hi;
    const size_t o = (((size_t)t * 4 + m) * 64 + l) * 8;
    #pragma unroll
    for (int j = 0; j < 8; ++j) {
      float f = p[j];
      unsigned short h = f2bf(f);
      bh[o + j] = h;
      bl[o + j] = f2bf(f - bf2f(h));
    }
  }
  if (hi == 0) {
    const float* p = cb + row * DIM;
    float s = 0.f;
    #pragma unroll
    for (int k = 0; k < DIM; ++k) s += p[k] * p[k];
    c2[row] = s;
  }
}

// LDS: res 34816 + c2s 4096 + z2s 512 + preds 512 = 39936 B
// (256,2): 256-reg cap -> double-buffered B-frags fit with zero spill.
__global__ __launch_bounds__(256, 2)
void rvq_mfma_kernel(const float* __restrict__ z,
                     const float* __restrict__ cbg,
                     const unsigned short* __restrict__ bh,
                     const unsigned short* __restrict__ bl,
                     const float* __restrict__ c2g,
                     float* __restrict__ out) {
  __shared__ __align__(16) float res[BM][RS];  // fp32 residual, per-wave 32-row panels
  __shared__ float c2s[N_CB];
  __shared__ float z2s[BM];
  __shared__ int   preds[BM];

  const int tid  = threadIdx.x;
  const int wave = tid >> 6;
  const int l    = tid & 63;
  const int tc   = l & 31;
  const int hi   = l >> 5;
  const int wr   = wave * 32;
  const int row0 = blockIdx.x * BM;

  float* zq   = out;
  float* maps = out + (size_t)B_TOTAL * DIM;

  // ---- stage z -> res (coalesced), c2 -> LDS ----
  {
    const float4* z4 = (const float4*)(z + (size_t)row0 * DIM);
    #pragma unroll
    for (int i = 0; i < 8; ++i) {
      const int f = i * 256 + tid;
      float4 v = z4[f];
      const int r = (f * 4) >> 6, d0 = (f * 4) & 63;
      *(float4*)&res[r][d0] = v;
    }
    for (int i = tid; i < N_CB; i += 256) c2s[i] = c2g[i];
  }
  __syncthreads();

  const bf16x8* bbase = (const bf16x8*)bh;
  const bf16x8* lbase = (const bf16x8*)bl;

  for (int depth = 0; depth < DEPTH; ++depth) {
    // ---- A fragments (split bf16) + fp32 row norm ----
    bf16x8 Ah[4], Al[4];
    float zp = 0.f;
    {
      const int arow = wr + tc;
      #pragma unroll
      for (int m = 0; m < 4; ++m) {
        u16x8 uh, ul;
        #pragma unroll
        for (int jj = 0; jj < 8; ++jj) {
          const float f = res[arow][16 * m + 8 * hi + jj];
          zp += f * f;
          const unsigned short h = f2bf(f);
          uh[jj] = h;
          ul[jj] = f2bf(f - bf2f(h));
        }
        Ah[m] = __builtin_bit_cast(bf16x8, uh);
        Al[m] = __builtin_bit_cast(bf16x8, ul);
      }
    }
    zp += __shfl_xor(zp, 32);          // partner lane holds the other 32 dims
    if (l < 32) z2s[wr + l] = zp;

    // acc seed: C-in = -z2(row)/2, so acc_final = dot - z2/2, d = c2 - 2*acc
    f32x16 accInit;
    #pragma unroll
    for (int s = 0; s < 16; ++s)
      accInit[s] = -0.5f * z2s[wr + (s & 3) + 8 * (s >> 2) + 4 * hi];

    // packed top-2 keys: (dist_bits & ~1023) | col ; uint order == (dist, col) order
    unsigned m1[16], m2[16];
    #pragma unroll
    for (int s = 0; s < 16; ++s) { m1[s] = 0xFFFFFFFFu; m2[s] = 0xFFFFFFFFu; }

    float* mbase = maps + ((size_t)depth * B_TOTAL + row0 + wr + 4 * hi) * N_CB + tc;

    // ---- prologue: load tile-0 fragments ----
    bf16x8 B0, B1, B2, B3, L0, L1, L2, L3;
    {
      const bf16x8* p = bbase + l;
      const bf16x8* q = lbase + l;
      B0 = p[0]; B1 = p[64]; B2 = p[128]; B3 = p[192];
      L0 = q[0]; L1 = q[64]; L2 = q[128]; L3 = q[192];
    }

    for (int t = 0; t < 32; ++t) {
      // ---- prefetch tile t+1 BEFORE this tile's stores: loads stay younger
      // than nothing, stores issued below are younger than these loads, so
      // next iteration's MFMA waitcnt never drains the store burst ----
      const int tn = (t + 1) & 31;
      const bf16x8* pn = bbase + (size_t)(tn * 4) * 64 + l;
      const bf16x8* qn = lbase + (size_t)(tn * 4) * 64 + l;
      const bf16x8 B0n = pn[0], B1n = pn[64], B2n = pn[128], B3n = pn[192];
      const bf16x8 L0n = qn[0], L1n = qn[64], L2n = qn[128], L3n = qn[192];

      f32x16 acc = MFMA(Ah[0], B0, accInit);
      acc = MFMA(Ah[1], B1, acc);
      acc = MFMA(Ah[2], B2, acc);
      acc = MFMA(Ah[3], B3, acc);
      acc = MFMA(Ah[0], L0, acc);
      acc = MFMA(Ah[1], L1, acc);
      acc = MFMA(Ah[2], L2, acc);
      acc = MFMA(Ah[3], L3, acc);
      acc = MFMA(Al[0], B0, acc);
      acc = MFMA(Al[1], B1, acc);
      acc = MFMA(Al[2], B2, acc);
      acc = MFMA(Al[3], B3, acc);

      const float c2v = c2s[32 * t + tc];
      const unsigned colp = (unsigned)(32 * t + tc);
      float* mp = mbase + 32 * t;
      #pragma unroll
      for (int s = 0; s < 16; ++s) {
        const float d = fmaf(-2.f, acc[s], c2v);
        mp[((s & 3) + 8 * (s >> 2)) * N_CB] = d;   // 2x128B segments per wave store
        const float dc = fmaxf(d, 0.f);
        const unsigned k = (__builtin_bit_cast(unsigned, dc) & 0xFFFFFC00u) | colp;
        const unsigned t2 = umax32(m1[s], k);
        m1[s] = umin32(m1[s], k);
        m2[s] = umin32(m2[s], t2);
      }

      B0 = B0n; B1 = B1n; B2 = B2n; B3 = B3n;
      L0 = L0n; L1 = L1n; L2 = L2n; L3 = L3n;
    }

    // ---- decide pred per row; fp64 exact refine when band is ambiguous ----
    #pragma unroll
    for (int s = 0; s < 16; ++s) {
      const int row = wr + (s & 3) + 8 * (s >> 2) + 4 * hi;
      unsigned g1 = m1[s], g2 = m2[s];
      #pragma unroll
      for (int msk = 1; msk < 32; msk <<= 1) {
        const unsigned o1 = (unsigned)__shfl_xor((int)g1, msk);
        const unsigned o2 = (unsigned)__shfl_xor((int)g2, msk);
        const unsigned hi2 = umax32(g1, o1);
        g1 = umin32(g1, o1);
        g2 = umin32(umin32(g2, o2), hi2);
      }
      int pred = (int)(g1 & 1023u);
      const float d1f = __builtin_bit_cast(float, g1 & 0xFFFFFC00u);
      const float d2f = __builtin_bit_cast(float, g2 & 0xFFFFFC00u);
      if (d2f <= d1f + EPS) {
        const float thr = d1f + EPS;
        const bool c1 = __builtin_bit_cast(float, m1[s] & 0xFFFFFC00u) <= thr;
        const bool c2b = __builtin_bit_cast(float, m2[s] & 0xFFFFFC00u) <= thr;
        const unsigned long long B1b = __ballot(c1);
        const unsigned long long B2b = __ballot(c2b);
        const unsigned sh = tid & 32;
        unsigned b1 = (unsigned)(B1b >> sh);
        unsigned b2 = (unsigned)(B2b >> sh);
        const float2 rv = *(const float2*)&res[row][2 * tc];
        double best = DBL_MAX; int bix = 0x7fffffff;
        unsigned rem = b1;
        while (rem) {
          const int lb = __ffs(rem) - 1; rem &= rem - 1;
          const int cidx = __shfl((int)(m1[s] & 1023u), lb, 32);
          const float2 cv = *(const float2*)(cbg + (size_t)cidx * DIM + 2 * tc);
          double dp = ((double)rv.x - cv.x) * ((double)rv.x - cv.x)
                    + ((double)rv.y - cv.y) * ((double)rv.y - cv.y);
          #pragma unroll
          for (int msk = 1; msk < 32; msk <<= 1) dp += __shfl_xor(dp, msk);
          if (dp < best || (dp == best && cidx < bix)) { best = dp; bix = cidx; }
        }
        rem = b2;
        while (rem) {
          const int lb = __ffs(rem) - 1; rem &= rem - 1;
          const int cidx = __shfl((int)(m2[s] & 1023u), lb, 32);
          const float2 cv = *(const float2*)(cbg + (size_t)cidx * DIM + 2 * tc);
          double dp = ((double)rv.x - cv.x) * ((double)rv.x - cv.x)
                    + ((double)rv.y - cv.y) * ((double)rv.y - cv.y);
          #pragma unroll
          for (int msk = 1; msk < 32; msk <<= 1) dp += __shfl_xor(dp, msk);
          if (dp < best || (dp == best && cidx < bix)) { best = dp; bix = cidx; }
        }
        pred = bix;
      }
      if (tc == 0) preds[row] = pred;
    }

    // ---- residual -= codebook[pred] (fp32 elementwise, bitwise = ref) ----
    {
      const int urow = wr + tc;
      const int p = preds[urow];
      const float4* crow = (const float4*)(cbg + (size_t)p * DIM + 32 * hi);
      #pragma unroll
      for (int q = 0; q < 8; ++q) {
        const float4 cv = crow[q];
        float4* rp = (float4*)&res[urow][32 * hi + 4 * q];
        float4 rv = *rp;
        rv.x -= cv.x; rv.y -= cv.y; rv.z -= cv.z; rv.w -= cv.w;
        *rp = rv;
      }
    }
    // depth-loop state is wave-private; no block barrier needed
  }

  __syncthreads();   // final epilogue reads the whole panel across waves

  // ---- z_q = z - residual_final ----
  {
    const float4* z4 = (const float4*)(z + (size_t)row0 * DIM);
    float4* o4 = (float4*)(zq + (size_t)row0 * DIM);
    #pragma unroll
    for (int i = 0; i < 8; ++i) {
      const int f = i * 256 + tid;
      float4 v = z4[f];
      const int r = (f * 4) >> 6, d0 = (f * 4) & 63;
      const float4 rv = *(const float4*)&res[r][d0];
      v.x -= rv.x; v.y -= rv.y; v.z -= rv.z; v.w -= rv.w;
      o4[f] = v;
    }
  }
}

extern "C" void kernel_launch(void* const* d_in, const int* in_sizes, int n_in,
                              void* d_out, int out_size, void* d_ws, size_t ws_size,
                              hipStream_t stream) {
  const float* z  = (const float*)d_in[0];
  const float* cb = (const float*)d_in[1];
  float* out = (float*)d_out;

  unsigned short* bh = (unsigned short*)d_ws;          // 65536 u16 = 128KB
  unsigned short* bl = bh + 65536;                     // 128KB
  float*          c2 = (float*)(bl + 65536);           // 4KB

  hipLaunchKernelGGL(prep_kernel, dim3(32), dim3(64), 0, stream, cb, bh, bl, c2);
  hipLaunchKernelGGL(rvq_mfma_kernel, dim3(B_TOTAL / BM), dim3(256), 0, stream,
                     z, cb, bh, bl, c2, out);
}